// Round 1
// baseline (7000.155 us; speedup 1.0000x reference)
//
#include <hip/hip_runtime.h>
#include <math.h>

#define S_  2048
#define B_  2
#define M_  512
#define H_  12
#define D_  64
#define DM_ 768
#define K_  2560

// ---------------------------------------------------------------------------
// GEMM: C[r][c] = sum_k A[r][k] * W[c][k] + bias[c], A:[R][768], W:[768][768]
// MODE 0 = Q  (dual outputs qu = C+u, qv = C+v, scattered to [B][H][S][D])
// MODE 1 = KV (A gathered from {memories, x}, scatter to [B][H][K][D])
// MODE 2 = R  (scatter to [H][K][D])
// MODE 3 = O  (plain row-major [R][768] -> d_out)
// ---------------------------------------------------------------------------
template<int MODE>
__global__ __launch_bounds__(256)
void gemm_nt(const float* __restrict__ A0, const float* __restrict__ A1,
             const float* __restrict__ W,  const float* __restrict__ bias,
             const float* __restrict__ uvec, const float* __restrict__ vvec,
             float* __restrict__ out0, float* __restrict__ out1)
{
    __shared__ float At[32][132];   // [k][row] pad 132 (16B-aligned rows of k-major)
    __shared__ float Wt[32][68];    // [k][col] pad 68

    const int tid = threadIdx.x;
    const int tx = tid & 15;        // col group: cols c0 + tx*4 + j
    const int ty = tid >> 4;        // row group: rows r0 + ty*8 + i
    const int r0 = blockIdx.x * 128;
    const int c0 = blockIdx.y * 64;

    float acc[8][4];
    #pragma unroll
    for (int i = 0; i < 8; ++i)
        #pragma unroll
        for (int j = 0; j < 4; ++j) acc[i][j] = 0.f;

    const int ar = tid & 127, ah = tid >> 7;   // A staging: row, k-half
    const int wc = tid & 63,  wq = tid >> 6;   // W staging: col, k-quarter

    const float* arow;
    {
        int r = r0 + ar;
        if (MODE == 1) arow = (r < M_ * B_) ? (A0 + (size_t)r * DM_)
                                            : (A1 + (size_t)(r - M_ * B_) * DM_);
        else           arow = A0 + (size_t)r * DM_;
    }
    const float* wrow = W + (size_t)(c0 + wc) * DM_;

    for (int k0 = 0; k0 < DM_; k0 += 32) {
        __syncthreads();
        #pragma unroll
        for (int q = 0; q < 4; ++q) {           // stage A: 128 rows x 32 k
            int kof = ah * 16 + q * 4;
            float4 a4 = *(const float4*)(arow + k0 + kof);
            At[kof + 0][ar] = a4.x; At[kof + 1][ar] = a4.y;
            At[kof + 2][ar] = a4.z; At[kof + 3][ar] = a4.w;
        }
        #pragma unroll
        for (int q = 0; q < 2; ++q) {           // stage W: 64 cols x 32 k
            int kof = wq * 8 + q * 4;
            float4 w4 = *(const float4*)(wrow + k0 + kof);
            Wt[kof + 0][wc] = w4.x; Wt[kof + 1][wc] = w4.y;
            Wt[kof + 2][wc] = w4.z; Wt[kof + 3][wc] = w4.w;
        }
        __syncthreads();
        #pragma unroll 8
        for (int k = 0; k < 32; ++k) {
            float4 a0 = *(const float4*)&At[k][ty * 8];
            float4 a1 = *(const float4*)&At[k][ty * 8 + 4];
            float4 w4 = *(const float4*)&Wt[k][tx * 4];
            float a[8] = {a0.x, a0.y, a0.z, a0.w, a1.x, a1.y, a1.z, a1.w};
            float w[4] = {w4.x, w4.y, w4.z, w4.w};
            #pragma unroll
            for (int i = 0; i < 8; ++i)
                #pragma unroll
                for (int j = 0; j < 4; ++j)
                    acc[i][j] = fmaf(a[i], w[j], acc[i][j]);
        }
    }

    // epilogue
    const int c = c0 + tx * 4;
    float4 bb = *(const float4*)(bias + c);
    #pragma unroll
    for (int i = 0; i < 8; ++i) {
        int r = r0 + ty * 8 + i;
        float4 val;
        val.x = acc[i][0] + bb.x; val.y = acc[i][1] + bb.y;
        val.z = acc[i][2] + bb.z; val.w = acc[i][3] + bb.w;
        if (MODE == 0) {
            float4 uu = *(const float4*)(uvec + c);
            float4 vv = *(const float4*)(vvec + c);
            int qi = r >> 1, qb = r & 1, qh = c >> 6, qd = c & 63;
            size_t off = ((size_t)(qb * H_ + qh) * S_ + qi) * D_ + qd;
            float4 o1, o2;
            o1.x = val.x + uu.x; o1.y = val.y + uu.y; o1.z = val.z + uu.z; o1.w = val.w + uu.w;
            o2.x = val.x + vv.x; o2.y = val.y + vv.y; o2.z = val.z + vv.z; o2.w = val.w + vv.w;
            *(float4*)(out0 + off) = o1;
            *(float4*)(out1 + off) = o2;
        } else if (MODE == 1) {
            int kj = r >> 1, kb2 = r & 1, kh = c >> 6, kd = c & 63;
            *(float4*)(out0 + ((size_t)(kb2 * H_ + kh) * K_ + kj) * D_ + kd) = val;
        } else if (MODE == 2) {
            int rh = c >> 6, rd = c & 63;
            *(float4*)(out0 + ((size_t)rh * K_ + r) * D_ + rd) = val;
        } else {
            *(float4*)(out0 + (size_t)r * DM_ + c) = val;
        }
    }
}

// ---------------------------------------------------------------------------
// Fused rel-pos attention with online softmax.
// Block = (b, h, 64-query tile); 4 waves x 16 query rows each.
// Phase 1 (lane = key): s = (qu.k + bd)/8, bd via analytic rel_shift:
//   diff = j - i:  diff<=512  -> qv[i]   . kr[diff+2047]
//                  diff==513  -> 0
//                  diff>=514  -> qv[i+1] . kr[diff-514]   (wrap "garbage" row)
// Phase 2 (lane = (row, d4)): o = o*f + P.V, final o/l.
// ---------------------------------------------------------------------------
__global__ __launch_bounds__(256)
void attn_fused(const float* __restrict__ qu, const float* __restrict__ qv,
                const float* __restrict__ kb, const float* __restrict__ vb,
                const float* __restrict__ kr, const int* __restrict__ amask,
                float* __restrict__ o)
{
    __shared__ float4 kt[16][64];      // K tile, f4-transposed [c4][key] (conflict-free)
    __shared__ float  vt[64][68];      // V tile row-major, pad 68 (16B-aligned rows)
    __shared__ float  pt[4][16][65];   // P tile per wave
    __shared__ float  fl[4][16];       // per-tile rescale factor
    __shared__ float  msh[4][16];      // running max
    __shared__ float  lsh[4][16];      // running denom

    const int tid  = threadIdx.x;
    const int w    = tid >> 6;
    const int lane = tid & 63;
    const int h = blockIdx.y, b = blockIdx.z;
    const int i0 = blockIdx.x * 64 + w * 16;

    const float* kbase = kb + ((size_t)(b * H_ + h) * K_) * D_;
    const float* vbase = vb + ((size_t)(b * H_ + h) * K_) * D_;
    const float* qub   = qu + ((size_t)(b * H_ + h) * S_) * D_;
    const float* qvb   = qv + ((size_t)(b * H_ + h) * S_) * D_;
    const float* krb   = kr + (size_t)h * K_ * D_;

    if (lane < 16) { msh[w][lane] = -3.0e38f; lsh[w][lane] = 0.f; }

    float4 oacc[4];
    #pragma unroll
    for (int g = 0; g < 4; ++g) oacc[g] = make_float4(0.f, 0.f, 0.f, 0.f);

    const int rl = lane >> 4;      // phase-2 row-in-group
    const int d4 = lane & 15;      // phase-2 d4 slot

    for (int t = 0; t < K_ / 64; ++t) {
        const int j0 = t * 64;
        __syncthreads();
        // stage K (transposed): row = lane, c4 = w + 4q
        #pragma unroll
        for (int q = 0; q < 4; ++q) {
            int c4 = w + 4 * q;
            kt[c4][lane] = *(const float4*)(kbase + (size_t)(j0 + lane) * D_ + c4 * 4);
        }
        // stage V (row-major): coalesced
        #pragma unroll
        for (int q = 0; q < 4; ++q) {
            int idx = q * 256 + tid;
            int row = idx >> 4, c4 = idx & 15;
            *(float4*)&vt[row][c4 * 4] =
                *(const float4*)(vbase + (size_t)(j0 + row) * D_ + c4 * 4);
        }
        __syncthreads();

        const int jo = j0 + lane;
        #pragma unroll 2
        for (int i = 0; i < 16; ++i) {
            const int io = i0 + i;
            const float* qur = qub + (size_t)io * D_;
            float ac = 0.f;
            #pragma unroll
            for (int c4 = 0; c4 < 16; ++c4) {
                float4 q4 = *(const float4*)(qur + c4 * 4);
                float4 k4 = kt[c4][lane];
                ac += q4.x * k4.x + q4.y * k4.y + q4.z * k4.z + q4.w * k4.w;
            }
            const int diff = jo - io;
            const float* qvr; const float* krr; float bs = 1.f;
            if (diff <= 512)      { qvr = qvb + (size_t)io * D_;      krr = krb + (size_t)(diff + 2047) * D_; }
            else if (diff == 513) { qvr = qvb + (size_t)io * D_;      krr = krb;  bs = 0.f; }
            else                  { qvr = qvb + (size_t)(io + 1) * D_; krr = krb + (size_t)(diff - 514) * D_; }
            float bd = 0.f;
            #pragma unroll
            for (int c4 = 0; c4 < 16; ++c4) {
                float4 q4 = *(const float4*)(qvr + c4 * 4);
                float4 r4 = *(const float4*)(krr + c4 * 4);
                bd += q4.x * r4.x + q4.y * r4.y + q4.z * r4.z + q4.w * r4.w;
            }
            float s = (ac + bs * bd) * 0.125f;
            if (j0 >= M_) {
                int mv = amask[((size_t)b * S_ + io) * S_ + (jo - M_)];
                s -= (1.f - (float)mv) * 1.0e9f;
            }
            float tm = s;
            #pragma unroll
            for (int off = 32; off > 0; off >>= 1) tm = fmaxf(tm, __shfl_xor(tm, off, 64));
            const float mold = msh[w][i];
            const float mnew = fmaxf(mold, tm);
            const float p = expf(s - mnew);
            float ts = p;
            #pragma unroll
            for (int off = 32; off > 0; off >>= 1) ts += __shfl_xor(ts, off, 64);
            const float f = expf(mold - mnew);
            pt[w][i][lane] = p;
            if (lane == 0) {
                msh[w][i] = mnew;
                lsh[w][i] = lsh[w][i] * f + ts;
                fl[w][i]  = f;
            }
        }
        __syncthreads();
        // phase 2: o = o*f + P.V
        #pragma unroll
        for (int g = 0; g < 4; ++g) {
            const int ir = g * 4 + rl;
            const float f = fl[w][ir];
            float4 o4 = oacc[g];
            o4.x *= f; o4.y *= f; o4.z *= f; o4.w *= f;
            #pragma unroll 8
            for (int j = 0; j < 64; ++j) {
                const float p  = pt[w][ir][j];
                const float4 v4 = *(const float4*)&vt[j][d4 * 4];
                o4.x = fmaf(p, v4.x, o4.x); o4.y = fmaf(p, v4.y, o4.y);
                o4.z = fmaf(p, v4.z, o4.z); o4.w = fmaf(p, v4.w, o4.w);
            }
            oacc[g] = o4;
        }
    }

    __syncthreads();
    #pragma unroll
    for (int g = 0; g < 4; ++g) {
        const int ir = g * 4 + rl;
        const float inv = 1.f / lsh[w][ir];
        float4 o4 = oacc[g];
        o4.x *= inv; o4.y *= inv; o4.z *= inv; o4.w *= inv;
        const int io = i0 + ir;
        *(float4*)(o + ((size_t)(b * S_ + io)) * DM_ + h * D_ + d4 * 4) = o4;
    }
}

// ---------------------------------------------------------------------------
extern "C" void kernel_launch(void* const* d_in, const int* in_sizes, int n_in,
                              void* d_out, int out_size, void* d_ws, size_t ws_size,
                              hipStream_t stream)
{
    const float* x     = (const float*)d_in[0];
    const float* mem   = (const float*)d_in[1];
    const float* rpe   = (const float*)d_in[2];
    const int*   amask = (const int*)  d_in[3];
    const float* Wq_w  = (const float*)d_in[5];
    const float* Wq_b  = (const float*)d_in[6];
    const float* Wke_w = (const float*)d_in[7];
    const float* Wke_b = (const float*)d_in[8];
    const float* Wv_w  = (const float*)d_in[9];
    const float* Wv_b  = (const float*)d_in[10];
    const float* Wkr_w = (const float*)d_in[11];
    const float* Wkr_b = (const float*)d_in[12];
    const float* u     = (const float*)d_in[13];
    const float* v     = (const float*)d_in[14];
    const float* Wo_w  = (const float*)d_in[15];
    const float* Wo_b  = (const float*)d_in[16];
    float* out = (float*)d_out;

    float* ws = (float*)d_ws;
    float* qu = ws;
    float* qv = qu + (size_t)B_ * H_ * S_ * D_;   // +3,145,728
    float* kb = qv + (size_t)B_ * H_ * S_ * D_;   // +3,145,728
    float* vb = kb + (size_t)B_ * H_ * K_ * D_;   // +3,932,160
    float* kr = vb + (size_t)B_ * H_ * K_ * D_;   // +3,932,160
    float* ob = kr + (size_t)H_ * K_ * D_;        // +1,966,080 (total ~77 MB)

    gemm_nt<0><<<dim3(S_ * B_ / 128, DM_ / 64), 256, 0, stream>>>(
        x, nullptr, Wq_w, Wq_b, u, v, qu, qv);
    gemm_nt<1><<<dim3(K_ * B_ / 128, DM_ / 64), 256, 0, stream>>>(
        mem, x, Wke_w, Wke_b, nullptr, nullptr, kb, nullptr);
    gemm_nt<1><<<dim3(K_ * B_ / 128, DM_ / 64), 256, 0, stream>>>(
        mem, x, Wv_w, Wv_b, nullptr, nullptr, vb, nullptr);
    gemm_nt<2><<<dim3(K_ / 128, DM_ / 64), 256, 0, stream>>>(
        rpe, nullptr, Wkr_w, Wkr_b, nullptr, nullptr, kr, nullptr);

    attn_fused<<<dim3(S_ / 64, H_, B_), 256, 0, stream>>>(
        qu, qv, kb, vb, kr, amask, ob);

    gemm_nt<3><<<dim3(S_ * B_ / 128, DM_ / 64), 256, 0, stream>>>(
        ob, nullptr, Wo_w, Wo_b, nullptr, nullptr, out, nullptr);
}

// Round 2
// 885.610 us; speedup vs baseline: 7.9043x; 7.9043x over previous
//
#include <hip/hip_runtime.h>
#include <math.h>

#define S_  2048
#define B_  2
#define M_  512
#define H_  12
#define D_  64
#define DM_ 768
#define K_  2560

typedef short bf16x8 __attribute__((ext_vector_type(8)));
typedef float f32x4  __attribute__((ext_vector_type(4)));
typedef unsigned short u16;
typedef unsigned short u16x4 __attribute__((ext_vector_type(4)));

static __device__ __forceinline__ u16 f2bf(float f) {
    unsigned u = __float_as_uint(f);
    u += 0x7fffu + ((u >> 16) & 1u);
    return (u16)(u >> 16);
}
static __device__ __forceinline__ float bf2f(u16 h) {
    return __uint_as_float(((unsigned)h) << 16);
}
static __device__ __forceinline__ void gll16(const u16* g, u16* l) {
    __builtin_amdgcn_global_load_lds(
        (const __attribute__((address_space(1))) unsigned int*)g,
        (__attribute__((address_space(3))) unsigned int*)l, 16, 0, 0);
}
#define MFMA16(a,b,c) __builtin_amdgcn_mfma_f32_16x16x32_bf16((a),(b),(c),0,0,0)

// ---------------------------------------------------------------------------
// fp32 GEMM: C[r][c] = sum_k A[r][k]*W[c][k] + bias[c]
// MODE 0 = Q  (dual bf16 outputs qu=C+u, qv=C+v -> [B][H][S][D])
// MODE 1 = KV (gather {mem,x}; bf16 -> [B][H][K][D])
// MODE 2 = R  (bf16 -> [H][K][D])
// MODE 3 = O  (fp32 row-major -> d_out)
// ---------------------------------------------------------------------------
template<int MODE>
__global__ __launch_bounds__(256)
void gemm_nt(const float* __restrict__ A0, const float* __restrict__ A1,
             const float* __restrict__ W,  const float* __restrict__ bias,
             const float* __restrict__ uvec, const float* __restrict__ vvec,
             void* __restrict__ out0v, void* __restrict__ out1v)
{
    __shared__ float At[32][132];
    __shared__ float Wt[32][68];

    const int tid = threadIdx.x;
    const int tx = tid & 15;
    const int ty = tid >> 4;
    const int r0 = blockIdx.x * 128;
    const int c0 = blockIdx.y * 64;

    float acc[8][4];
    #pragma unroll
    for (int i = 0; i < 8; ++i)
        #pragma unroll
        for (int j = 0; j < 4; ++j) acc[i][j] = 0.f;

    const int ar = tid & 127, ah = tid >> 7;
    const int wc = tid & 63,  wq = tid >> 6;

    const float* arow;
    {
        int r = r0 + ar;
        if (MODE == 1) arow = (r < M_ * B_) ? (A0 + (size_t)r * DM_)
                                            : (A1 + (size_t)(r - M_ * B_) * DM_);
        else           arow = A0 + (size_t)r * DM_;
    }
    const float* wrow = W + (size_t)(c0 + wc) * DM_;

    for (int k0 = 0; k0 < DM_; k0 += 32) {
        __syncthreads();
        #pragma unroll
        for (int q = 0; q < 4; ++q) {
            int kof = ah * 16 + q * 4;
            float4 a4 = *(const float4*)(arow + k0 + kof);
            At[kof + 0][ar] = a4.x; At[kof + 1][ar] = a4.y;
            At[kof + 2][ar] = a4.z; At[kof + 3][ar] = a4.w;
        }
        #pragma unroll
        for (int q = 0; q < 2; ++q) {
            int kof = wq * 8 + q * 4;
            float4 w4 = *(const float4*)(wrow + k0 + kof);
            Wt[kof + 0][wc] = w4.x; Wt[kof + 1][wc] = w4.y;
            Wt[kof + 2][wc] = w4.z; Wt[kof + 3][wc] = w4.w;
        }
        __syncthreads();
        #pragma unroll 8
        for (int k = 0; k < 32; ++k) {
            float4 a0 = *(const float4*)&At[k][ty * 8];
            float4 a1 = *(const float4*)&At[k][ty * 8 + 4];
            float4 w4 = *(const float4*)&Wt[k][tx * 4];
            float a[8] = {a0.x, a0.y, a0.z, a0.w, a1.x, a1.y, a1.z, a1.w};
            float wv[4] = {w4.x, w4.y, w4.z, w4.w};
            #pragma unroll
            for (int i = 0; i < 8; ++i)
                #pragma unroll
                for (int j = 0; j < 4; ++j)
                    acc[i][j] = fmaf(a[i], wv[j], acc[i][j]);
        }
    }

    const int c = c0 + tx * 4;
    float4 bb = *(const float4*)(bias + c);
    #pragma unroll
    for (int i = 0; i < 8; ++i) {
        int r = r0 + ty * 8 + i;
        float4 val;
        val.x = acc[i][0] + bb.x; val.y = acc[i][1] + bb.y;
        val.z = acc[i][2] + bb.z; val.w = acc[i][3] + bb.w;
        if (MODE == 0) {
            float4 uu = *(const float4*)(uvec + c);
            float4 vv = *(const float4*)(vvec + c);
            int qi = r >> 1, qb = r & 1, qh = c >> 6, qd = c & 63;
            size_t off = ((size_t)(qb * H_ + qh) * S_ + qi) * D_ + qd;
            u16x4 o1, o2;
            o1[0] = f2bf(val.x + uu.x); o1[1] = f2bf(val.y + uu.y);
            o1[2] = f2bf(val.z + uu.z); o1[3] = f2bf(val.w + uu.w);
            o2[0] = f2bf(val.x + vv.x); o2[1] = f2bf(val.y + vv.y);
            o2[2] = f2bf(val.z + vv.z); o2[3] = f2bf(val.w + vv.w);
            *(u16x4*)((u16*)out0v + off) = o1;
            *(u16x4*)((u16*)out1v + off) = o2;
        } else if (MODE == 1) {
            int kj = r >> 1, kb2 = r & 1, kh = c >> 6, kd = c & 63;
            size_t off = ((size_t)(kb2 * H_ + kh) * K_ + kj) * D_ + kd;
            u16x4 o1;
            o1[0] = f2bf(val.x); o1[1] = f2bf(val.y);
            o1[2] = f2bf(val.z); o1[3] = f2bf(val.w);
            *(u16x4*)((u16*)out0v + off) = o1;
        } else if (MODE == 2) {
            int rh = c >> 6, rd = c & 63;
            size_t off = ((size_t)rh * K_ + r) * D_ + rd;
            u16x4 o1;
            o1[0] = f2bf(val.x); o1[1] = f2bf(val.y);
            o1[2] = f2bf(val.z); o1[3] = f2bf(val.w);
            *(u16x4*)((u16*)out0v + off) = o1;
        } else {
            *(float4*)((float*)out0v + (size_t)r * DM_ + c) = val;
        }
    }
}

// ---------------------------------------------------------------------------
// mask -> bitmask (1 bit per element)
// ---------------------------------------------------------------------------
__global__ __launch_bounds__(256)
void maskpack(const int* __restrict__ am, unsigned long long* __restrict__ mb)
{
    const size_t idx = (size_t)blockIdx.x * 256 + threadIdx.x;
    const int v = am[idx];
    const unsigned long long bal = __ballot(v != 0);
    if ((threadIdx.x & 63) == 0) mb[idx >> 6] = bal;
}

// ---------------------------------------------------------------------------
// bf16 MFMA flash attention with analytic rel-shift band.
// Block = (i-tile of 64 q rows, h, b); 4 waves x 16 q rows.
// ---------------------------------------------------------------------------
__global__ __launch_bounds__(256, 2)
void attn_mfma(const u16* __restrict__ qu, const u16* __restrict__ qv,
               const u16* __restrict__ kb, const u16* __restrict__ vb,
               const u16* __restrict__ kr, const unsigned long long* __restrict__ mbq,
               float* __restrict__ ob)
{
    __shared__ __align__(16) u16  kt[64 * 64];      // K tile,  swz [key][d]
    __shared__ __align__(16) u16  band[128 * 64];   // kr band, swz [dd][d]
    __shared__ __align__(16) u16  vt[64 * 64];      // V^T,     swz [d][key]
    __shared__ __align__(16) float bdl[64 * 128];   // BD,      [ql][dd]
    __shared__ __align__(16) float row64[128];      // BD row 64 (wrap @ ql=63)
    __shared__ __align__(16) float qv64f[64];       // qv row i0+64 (fp32)
    __shared__ __align__(16) u16  plds[4 * 16 * 64];// P per wave, swz [q16][key]

    const int tid  = threadIdx.x;
    const int w    = tid >> 6, lane = tid & 63;
    const int l15  = lane & 15, lq = lane >> 4;
    const int h = blockIdx.y, b = blockIdx.z;
    const int i0 = blockIdx.x * 64;

    const size_t bh = (size_t)(b * H_ + h);
    const u16* qub = qu + bh * S_ * 64;
    const u16* qvb = qv + bh * S_ * 64;
    const u16* kbb = kb + bh * K_ * 64;
    const u16* vbb = vb + bh * K_ * 64;
    const u16* krb = kr + (size_t)h * K_ * 64;
    const unsigned* mrow = ((const unsigned*)mbq) + ((size_t)b * S_ + i0) * 64;

    // per-wave A fragments (qu, qv), 2 d-halves: row = i0+16w+l15, k = 8*lq+e
    bf16x8 quA[2], qvA[2];
    {
        const size_t qr = (size_t)(i0 + w * 16 + l15) * 64 + lq * 8;
        quA[0] = *(const bf16x8*)(qub + qr);
        quA[1] = *(const bf16x8*)(qub + qr + 32);
        qvA[0] = *(const bf16x8*)(qvb + qr);
        qvA[1] = *(const bf16x8*)(qvb + qr + 32);
    }
    if (tid < 64) {
        int qr = i0 + 64; if (qr > S_ - 1) qr = S_ - 1;   // clamped row never used
        qv64f[tid] = bf2f(qvb[(size_t)qr * 64 + tid]);
    }

    float m_run[4], l_run[4];
    #pragma unroll
    for (int r = 0; r < 4; ++r) { m_run[r] = -3.0e38f; l_run[r] = 0.f; }
    f32x4 oacc[4];
    #pragma unroll
    for (int cg = 0; cg < 4; ++cg) oacc[cg] = (f32x4){0.f, 0.f, 0.f, 0.f};

    for (int t = 0; t < K_ / 64; ++t) {
        const int j0 = t * 64;
        const int diff_base = j0 - i0 - 63;
        __syncthreads();
        // --- stage K tile (global_load_lds, pre-swizzled source) ---
        #pragma unroll
        for (int q = 0; q < 2; ++q) {
            const int inst = w * 2 + q;
            const int key = inst * 8 + (lane >> 3);
            const int chunk = (lane & 7) ^ (key & 7);
            gll16(kbb + (size_t)(j0 + key) * 64 + chunk * 8, &kt[inst * 512]);
        }
        // --- stage kr band (per-lane regime addressing) ---
        #pragma unroll
        for (int q = 0; q < 4; ++q) {
            const int inst = w * 4 + q;
            const int dd = inst * 8 + (lane >> 3);
            const int chunk = (lane & 7) ^ (dd & 7);
            const int diff = diff_base + dd;
            int rrow;
            if (diff <= 512)      rrow = diff + 2047;
            else if (diff == 513) rrow = 0;          // value never read
            else                  rrow = diff - 514;
            gll16(krb + (size_t)rrow * 64 + chunk * 8, &band[inst * 512]);
        }
        // --- stage V^T (scalar transpose, swizzled) ---
        {
            const int key = tid & 63, dq = tid >> 6;
            const u16* vrow = vbb + (size_t)(j0 + key) * 64 + dq * 16;
            const bf16x8 va  = *(const bf16x8*)vrow;
            const bf16x8 va2 = *(const bf16x8*)(vrow + 8);
            #pragma unroll
            for (int e = 0; e < 8; ++e) {
                const int d = dq * 16 + e, d2 = d + 8;
                vt[d * 64 + (key ^ ((d & 7) << 3))]   = (u16)va[e];
                vt[d2 * 64 + (key ^ ((d2 & 7) << 3))] = (u16)va2[e];
            }
        }
        __syncthreads();

        // --- MFMA: AC = QU @ K^T ---
        f32x4 ac[4];
        #pragma unroll
        for (int cg = 0; cg < 4; ++cg) ac[cg] = (f32x4){0.f, 0.f, 0.f, 0.f};
        #pragma unroll
        for (int h2 = 0; h2 < 2; ++h2) {
            const int d0 = lq * 8 + h2 * 32;
            #pragma unroll
            for (int cg = 0; cg < 4; ++cg) {
                const int key = cg * 16 + l15;
                const bf16x8 bB = *(const bf16x8*)&kt[key * 64 + (d0 ^ ((key & 7) << 3))];
                ac[cg] = MFMA16(quA[h2], bB, ac[cg]);
            }
        }
        // --- MFMA: BD = QV @ band^T ---
        f32x4 bd[8];
        #pragma unroll
        for (int cg = 0; cg < 8; ++cg) bd[cg] = (f32x4){0.f, 0.f, 0.f, 0.f};
        #pragma unroll
        for (int h2 = 0; h2 < 2; ++h2) {
            const int d0 = lq * 8 + h2 * 32;
            #pragma unroll
            for (int cg = 0; cg < 8; ++cg) {
                const int dd = cg * 16 + l15;
                const bf16x8 bB = *(const bf16x8*)&band[dd * 64 + (d0 ^ ((dd & 7) << 3))];
                bd[cg] = MFMA16(qvA[h2], bB, bd[cg]);
            }
        }
        #pragma unroll
        for (int cg = 0; cg < 8; ++cg)
            #pragma unroll
            for (int r = 0; r < 4; ++r)
                bdl[(w * 16 + lq * 4 + r) * 128 + cg * 16 + l15] = bd[cg][r];
        // --- BD row 64 (VALU co-op): qv[i0+64] . band[dd] ---
        {
            const int dd = tid >> 1, half = tid & 1;
            float accv = 0.f;
            #pragma unroll
            for (int c2 = 0; c2 < 4; ++c2) {
                const int d0 = half * 32 + c2 * 8;
                const bf16x8 bv = *(const bf16x8*)&band[dd * 64 + (d0 ^ ((dd & 7) << 3))];
                #pragma unroll
                for (int e = 0; e < 8; ++e)
                    accv = fmaf(bf2f((u16)bv[e]), qv64f[d0 + e], accv);
            }
            accv += __shfl_xor(accv, 1, 64);
            if (half == 0) row64[dd] = accv;
        }
        __syncthreads();

        // --- extraction + online softmax ---
        float f_r[4];
        #pragma unroll
        for (int r = 0; r < 4; ++r) {
            const int q16 = lq * 4 + r;
            const int ql  = w * 16 + q16;
            float sr[4];
            #pragma unroll
            for (int cg = 0; cg < 4; ++cg) {
                const int key = cg * 16 + l15;
                const int dd  = key - ql + 63;
                const int diff = diff_base + dd;
                float bdv;
                if (diff == 513)      bdv = 0.f;
                else if (diff >= 514) bdv = (ql == 63) ? row64[dd] : bdl[(ql + 1) * 128 + dd];
                else                  bdv = bdl[ql * 128 + dd];
                float s = (ac[cg][r] + bdv) * 0.125f;
                const int ka = j0 + key;
                if (ka >= M_) {
                    const int jj = ka - M_;
                    const unsigned wv = mrow[ql * 64 + (jj >> 5)];
                    if (!((wv >> (jj & 31)) & 1u)) s -= 1.0e9f;
                }
                sr[cg] = s;
            }
            float mx = fmaxf(fmaxf(sr[0], sr[1]), fmaxf(sr[2], sr[3]));
            mx = fmaxf(mx, __shfl_xor(mx, 1, 64));
            mx = fmaxf(mx, __shfl_xor(mx, 2, 64));
            mx = fmaxf(mx, __shfl_xor(mx, 4, 64));
            mx = fmaxf(mx, __shfl_xor(mx, 8, 64));
            const float mn = fmaxf(m_run[r], mx);
            const float fr = __expf(m_run[r] - mn);
            m_run[r] = mn;
            float lt = 0.f;
            #pragma unroll
            for (int cg = 0; cg < 4; ++cg) {
                const float p = __expf(sr[cg] - mn);
                lt += p;
                plds[w * 1024 + q16 * 64 + ((cg * 16 + l15) ^ ((q16 & 7) << 3))] = f2bf(p);
            }
            lt += __shfl_xor(lt, 1, 64);
            lt += __shfl_xor(lt, 2, 64);
            lt += __shfl_xor(lt, 4, 64);
            lt += __shfl_xor(lt, 8, 64);
            l_run[r] = l_run[r] * fr + lt;
            f_r[r] = fr;
        }
        #pragma unroll
        for (int cg = 0; cg < 4; ++cg)
            #pragma unroll
            for (int r = 0; r < 4; ++r) oacc[cg][r] *= f_r[r];

        __syncthreads();
        // --- MFMA: O += P @ V ---
        #pragma unroll
        for (int kh = 0; kh < 2; ++kh) {
            const int key0 = lq * 8 + kh * 32;
            const bf16x8 pA = *(const bf16x8*)&plds[w * 1024 + l15 * 64 + (key0 ^ ((l15 & 7) << 3))];
            #pragma unroll
            for (int cg = 0; cg < 4; ++cg) {
                const int d = cg * 16 + l15;
                const bf16x8 vB = *(const bf16x8*)&vt[d * 64 + (key0 ^ ((d & 7) << 3))];
                oacc[cg] = MFMA16(pA, vB, oacc[cg]);
            }
        }
    }

    #pragma unroll
    for (int cg = 0; cg < 4; ++cg)
        #pragma unroll
        for (int r = 0; r < 4; ++r) {
            const int ql = w * 16 + lq * 4 + r;
            ob[((size_t)b * S_ + i0 + ql) * DM_ + h * 64 + cg * 16 + l15] =
                oacc[cg][r] / l_run[r];
        }
}

// ---------------------------------------------------------------------------
extern "C" void kernel_launch(void* const* d_in, const int* in_sizes, int n_in,
                              void* d_out, int out_size, void* d_ws, size_t ws_size,
                              hipStream_t stream)
{
    const float* x     = (const float*)d_in[0];
    const float* mem   = (const float*)d_in[1];
    const float* rpe   = (const float*)d_in[2];
    const int*   amask = (const int*)  d_in[3];
    const float* Wq_w  = (const float*)d_in[5];
    const float* Wq_b  = (const float*)d_in[6];
    const float* Wke_w = (const float*)d_in[7];
    const float* Wke_b = (const float*)d_in[8];
    const float* Wv_w  = (const float*)d_in[9];
    const float* Wv_b  = (const float*)d_in[10];
    const float* Wkr_w = (const float*)d_in[11];
    const float* Wkr_b = (const float*)d_in[12];
    const float* u     = (const float*)d_in[13];
    const float* v     = (const float*)d_in[14];
    const float* Wo_w  = (const float*)d_in[15];
    const float* Wo_b  = (const float*)d_in[16];
    float* out = (float*)d_out;

    u16* quB = (u16*)d_ws;                               // 3,145,728 bf16
    u16* qvB = quB + 3145728;
    u16* kbB = qvB + 3145728;                            // 3,932,160
    u16* vbB = kbB + 3932160;
    u16* krB = vbB + 3932160;                            // 1,966,080
    unsigned long long* mbB = (unsigned long long*)(krB + 1966080);  // 131,072 u64
    float* obB = (float*)(mbB + 131072);                 // 3,145,728 f32

    maskpack<<<B_ * S_ * S_ / 256, 256, 0, stream>>>(amask, mbB);

    gemm_nt<0><<<dim3(S_ * B_ / 128, DM_ / 64), 256, 0, stream>>>(
        x, nullptr, Wq_w, Wq_b, u, v, quB, qvB);
    gemm_nt<1><<<dim3(K_ * B_ / 128, DM_ / 64), 256, 0, stream>>>(
        mem, x, Wke_w, Wke_b, nullptr, nullptr, kbB, nullptr);
    gemm_nt<1><<<dim3(K_ * B_ / 128, DM_ / 64), 256, 0, stream>>>(
        mem, x, Wv_w, Wv_b, nullptr, nullptr, vbB, nullptr);
    gemm_nt<2><<<dim3(K_ / 128, DM_ / 64), 256, 0, stream>>>(
        rpe, nullptr, Wkr_w, Wkr_b, nullptr, nullptr, krB, nullptr);

    attn_mfma<<<dim3(S_ / 64, H_, B_), 256, 0, stream>>>(
        quB, qvB, kbB, vbB, krB, mbB, obB);

    gemm_nt<3><<<dim3(S_ * B_ / 128, DM_ / 64), 256, 0, stream>>>(
        obB, nullptr, Wo_w, Wo_b, nullptr, nullptr, out, nullptr);
}

// Round 3
// 726.458 us; speedup vs baseline: 9.6360x; 1.2191x over previous
//
#include <hip/hip_runtime.h>
#include <math.h>

#define S_  2048
#define B_  2
#define M_  512
#define H_  12
#define D_  64
#define DM_ 768
#define K_  2560

typedef short bf16x8 __attribute__((ext_vector_type(8)));
typedef float f32x4  __attribute__((ext_vector_type(4)));
typedef unsigned short u16;
typedef unsigned short u16x4 __attribute__((ext_vector_type(4)));
typedef unsigned long long u64;

static __device__ __forceinline__ u16 f2bf(float f) {
    unsigned u = __float_as_uint(f);
    u += 0x7fffu + ((u >> 16) & 1u);
    return (u16)(u >> 16);
}
static __device__ __forceinline__ float bf2f(u16 h) {
    return __uint_as_float(((unsigned)h) << 16);
}
static __device__ __forceinline__ void gll16(const u16* g, u16* l) {
    __builtin_amdgcn_global_load_lds(
        (const __attribute__((address_space(1))) unsigned int*)g,
        (__attribute__((address_space(3))) unsigned int*)l, 16, 0, 0);
}
#define MFMA16(a,b,c) __builtin_amdgcn_mfma_f32_16x16x32_bf16((a),(b),(c),0,0,0)

// ---------------------------------------------------------------------------
// cast fp32 -> bf16, 7 segments in one launch
// ---------------------------------------------------------------------------
struct Cast7 {
    const float* src[7];
    u16*         dst[7];
    int          n4[7];    // float4 groups
};
__global__ __launch_bounds__(256)
void castk(Cast7 c)
{
    const int seg = blockIdx.y;
    const int i = blockIdx.x * 256 + threadIdx.x;
    if (i >= c.n4[seg]) return;
    const float4 v = *(const float4*)(c.src[seg] + (size_t)i * 4);
    u16x4 o;
    o[0] = f2bf(v.x); o[1] = f2bf(v.y); o[2] = f2bf(v.z); o[3] = f2bf(v.w);
    *(u16x4*)(c.dst[seg] + (size_t)i * 4) = o;
}

// ---------------------------------------------------------------------------
// bf16 MFMA GEMM: C^T[c][r] = sum_k W[c,k]*A[r,k] + bias[c]
// 128x128 tile, 4 waves (2x2), 16 MFMA/K-step/wave, gll staging, XOR chunks.
// MODE 0 = Q (dual bf16 out qu=C+u, qv=C+v -> [B][H][S][D])
// MODE 1 = KV (A = concat(mem,x) rows; bf16 -> [B][H][K][D])
// MODE 2 = R  (bf16 -> [H][K][D])
// ---------------------------------------------------------------------------
template<int MODE>
__global__ __launch_bounds__(256)
void gemm_bf16(const u16* __restrict__ Wb, const u16* __restrict__ Ab,
               const float* __restrict__ bias,
               const float* __restrict__ uvec, const float* __restrict__ vvec,
               u16* __restrict__ out0, u16* __restrict__ out1)
{
    __shared__ __align__(16) u16 Wt[128 * 32];
    __shared__ __align__(16) u16 At[128 * 32];

    const int tid = threadIdx.x;
    const int w = tid >> 6, lane = tid & 63;
    const int l15 = lane & 15, lq = lane >> 4;
    const int wm = w >> 1, wn = w & 1;
    const int c0 = blockIdx.x * 128, r0 = blockIdx.y * 128;

    f32x4 acc[4][4];
    #pragma unroll
    for (int mi = 0; mi < 4; ++mi)
        #pragma unroll
        for (int ni = 0; ni < 4; ++ni) acc[mi][ni] = (f32x4){0.f, 0.f, 0.f, 0.f};

    for (int k0 = 0; k0 < DM_; k0 += 32) {
        __syncthreads();
        #pragma unroll
        for (int q = 0; q < 2; ++q) {
            const int sl = (w * 2 + q) * 64 + lane;   // 16B slot
            const int row = sl >> 2, cp = sl & 3, ch = cp ^ (row & 3);
            gll16(Wb + (size_t)(c0 + row) * DM_ + k0 + ch * 8, Wt + (w * 2 + q) * 512);
            gll16(Ab + (size_t)(r0 + row) * DM_ + k0 + ch * 8, At + (w * 2 + q) * 512);
        }
        __syncthreads();
        bf16x8 wf[4], af[4];
        #pragma unroll
        for (int mi = 0; mi < 4; ++mi) {
            const int row = wm * 64 + mi * 16 + l15;
            wf[mi] = *(const bf16x8*)&Wt[row * 32 + (lq ^ (row & 3)) * 8];
        }
        #pragma unroll
        for (int ni = 0; ni < 4; ++ni) {
            const int row = wn * 64 + ni * 16 + l15;
            af[ni] = *(const bf16x8*)&At[row * 32 + (lq ^ (row & 3)) * 8];
        }
        #pragma unroll
        for (int mi = 0; mi < 4; ++mi)
            #pragma unroll
            for (int ni = 0; ni < 4; ++ni)
                acc[mi][ni] = MFMA16(wf[mi], af[ni], acc[mi][ni]);
    }

    // epilogue: c = c0+wm*64+mi*16+lq*4+reg (model dim), token = r0+wn*64+ni*16+l15
    #pragma unroll
    for (int mi = 0; mi < 4; ++mi) {
        const int cb = c0 + wm * 64 + mi * 16 + lq * 4;
        const float4 bb = *(const float4*)(bias + cb);
        const int qh = cb >> 6, qd = cb & 63;
        #pragma unroll
        for (int ni = 0; ni < 4; ++ni) {
            const int r = r0 + wn * 64 + ni * 16 + l15;
            const f32x4 a = acc[mi][ni];
            const float v0 = a[0] + bb.x, v1 = a[1] + bb.y;
            const float v2 = a[2] + bb.z, v3 = a[3] + bb.w;
            if (MODE == 0) {
                const float4 uu = *(const float4*)(uvec + cb);
                const float4 vv = *(const float4*)(vvec + cb);
                const int s = r >> 1, b = r & 1;
                const size_t off = ((size_t)(b * H_ + qh) * S_ + s) * D_ + qd;
                u16x4 o1, o2;
                o1[0] = f2bf(v0 + uu.x); o1[1] = f2bf(v1 + uu.y);
                o1[2] = f2bf(v2 + uu.z); o1[3] = f2bf(v3 + uu.w);
                o2[0] = f2bf(v0 + vv.x); o2[1] = f2bf(v1 + vv.y);
                o2[2] = f2bf(v2 + vv.z); o2[3] = f2bf(v3 + vv.w);
                *(u16x4*)(out0 + off) = o1;
                *(u16x4*)(out1 + off) = o2;
            } else if (MODE == 1) {
                int j, b;
                if (r < M_ * B_) { j = r >> 1; b = r & 1; }
                else { const int rr = r - M_ * B_; j = M_ + (rr >> 1); b = rr & 1; }
                const size_t off = ((size_t)(b * H_ + qh) * K_ + j) * D_ + qd;
                u16x4 o1;
                o1[0] = f2bf(v0); o1[1] = f2bf(v1); o1[2] = f2bf(v2); o1[3] = f2bf(v3);
                *(u16x4*)(out0 + off) = o1;
            } else {
                const size_t off = ((size_t)qh * K_ + r) * D_ + qd;
                u16x4 o1;
                o1[0] = f2bf(v0); o1[1] = f2bf(v1); o1[2] = f2bf(v2); o1[3] = f2bf(v3);
                *(u16x4*)(out0 + off) = o1;
            }
        }
    }
}

// ---------------------------------------------------------------------------
// fp32 GEMM for the output projection (keeps final absmax tight)
// ---------------------------------------------------------------------------
__global__ __launch_bounds__(256)
void gemm_o(const float* __restrict__ A0, const float* __restrict__ W,
            const float* __restrict__ bias, float* __restrict__ out)
{
    __shared__ float At[32][132];
    __shared__ float Wt[32][68];

    const int tid = threadIdx.x;
    const int tx = tid & 15;
    const int ty = tid >> 4;
    const int r0 = blockIdx.x * 128;
    const int c0 = blockIdx.y * 64;

    float acc[8][4];
    #pragma unroll
    for (int i = 0; i < 8; ++i)
        #pragma unroll
        for (int j = 0; j < 4; ++j) acc[i][j] = 0.f;

    const int ar = tid & 127, ah = tid >> 7;
    const int wc = tid & 63,  wq = tid >> 6;
    const float* arow = A0 + (size_t)(r0 + ar) * DM_;
    const float* wrow = W + (size_t)(c0 + wc) * DM_;

    for (int k0 = 0; k0 < DM_; k0 += 32) {
        __syncthreads();
        #pragma unroll
        for (int q = 0; q < 4; ++q) {
            int kof = ah * 16 + q * 4;
            float4 a4 = *(const float4*)(arow + k0 + kof);
            At[kof + 0][ar] = a4.x; At[kof + 1][ar] = a4.y;
            At[kof + 2][ar] = a4.z; At[kof + 3][ar] = a4.w;
        }
        #pragma unroll
        for (int q = 0; q < 2; ++q) {
            int kof = wq * 8 + q * 4;
            float4 w4 = *(const float4*)(wrow + k0 + kof);
            Wt[kof + 0][wc] = w4.x; Wt[kof + 1][wc] = w4.y;
            Wt[kof + 2][wc] = w4.z; Wt[kof + 3][wc] = w4.w;
        }
        __syncthreads();
        #pragma unroll 8
        for (int k = 0; k < 32; ++k) {
            float4 a0 = *(const float4*)&At[k][ty * 8];
            float4 a1 = *(const float4*)&At[k][ty * 8 + 4];
            float4 w4 = *(const float4*)&Wt[k][tx * 4];
            float a[8] = {a0.x, a0.y, a0.z, a0.w, a1.x, a1.y, a1.z, a1.w};
            float wv[4] = {w4.x, w4.y, w4.z, w4.w};
            #pragma unroll
            for (int i = 0; i < 8; ++i)
                #pragma unroll
                for (int j = 0; j < 4; ++j)
                    acc[i][j] = fmaf(a[i], wv[j], acc[i][j]);
        }
    }

    const int c = c0 + tx * 4;
    float4 bb = *(const float4*)(bias + c);
    #pragma unroll
    for (int i = 0; i < 8; ++i) {
        int r = r0 + ty * 8 + i;
        float4 val;
        val.x = acc[i][0] + bb.x; val.y = acc[i][1] + bb.y;
        val.z = acc[i][2] + bb.z; val.w = acc[i][3] + bb.w;
        *(float4*)(out + (size_t)r * DM_ + c) = val;
    }
}

// ---------------------------------------------------------------------------
// mask -> bitmask
// ---------------------------------------------------------------------------
__global__ __launch_bounds__(256)
void maskpack(const int* __restrict__ am, u64* __restrict__ mb)
{
    const size_t idx = (size_t)blockIdx.x * 256 + threadIdx.x;
    const int v = am[idx];
    const u64 bal = __ballot(v != 0);
    if ((threadIdx.x & 63) == 0) mb[idx >> 6] = bal;
}

// ---------------------------------------------------------------------------
// bf16 MFMA flash attention; writer-side rel-shift scatter into sc[64][66]
// (sc aliases the dead K+band LDS). Tile regimes:
//   MODE 0: all diff <= 512 (normal), MODE 1: all diff >= 514 (wrap),
//   MODE 2: mixed (j0-i0 in {512,576}).
// ---------------------------------------------------------------------------
template<int MODE>
static __device__ __forceinline__ void attn_tile_step(
    const int t, const int i0, const int tid,
    const u16* __restrict__ kbb, const u16* __restrict__ vbb,
    const u16* __restrict__ krb, const u64* __restrict__ mrow64,
    const bf16x8 (&quA)[2], const bf16x8 (&qvA)[2],
    u16* kt, u16* band, u16* vt, float* sc, float* r64s, u16* plds,
    const float* qv64f,
    f32x4 (&oacc)[4], float (&m_run)[4], float (&l_run)[4])
{
    const int w = tid >> 6, lane = tid & 63;
    const int l15 = lane & 15, lq = lane >> 4;
    const int j0 = t * 64;
    const int diff_base = j0 - i0 - 63;

    __syncthreads();
    // --- stage K tile ---
    #pragma unroll
    for (int q = 0; q < 2; ++q) {
        const int inst = w * 2 + q;
        const int key = inst * 8 + (lane >> 3);
        const int chunk = (lane & 7) ^ (key & 7);
        gll16(kbb + (size_t)(j0 + key) * 64 + chunk * 8, kt + inst * 512);
    }
    // --- stage kr band ---
    #pragma unroll
    for (int q = 0; q < 4; ++q) {
        const int inst = w * 4 + q;
        const int dd = inst * 8 + (lane >> 3);
        const int chunk = (lane & 7) ^ (dd & 7);
        const int diff = diff_base + dd;
        int rrow;
        if (MODE == 0)      rrow = diff + 2047;
        else if (MODE == 1) rrow = diff - 514;
        else rrow = (diff <= 512) ? (diff + 2047) : ((diff == 513) ? 0 : (diff - 514));
        gll16(krb + (size_t)rrow * 64 + chunk * 8, band + inst * 512);
    }
    // --- stage V^T ---
    {
        const int key = tid & 63, dq = tid >> 6;
        const u16* vrow = vbb + (size_t)(j0 + key) * 64 + dq * 16;
        const bf16x8 va  = *(const bf16x8*)vrow;
        const bf16x8 va2 = *(const bf16x8*)(vrow + 8);
        #pragma unroll
        for (int e = 0; e < 8; ++e) {
            const int d = dq * 16 + e, d2 = d + 8;
            vt[d * 64 + (key ^ ((d & 7) << 3))]   = (u16)va[e];
            vt[d2 * 64 + (key ^ ((d2 & 7) << 3))] = (u16)va2[e];
        }
    }
    __syncthreads();

    // --- MFMA: AC = QU @ K^T ---
    f32x4 ac[4];
    #pragma unroll
    for (int cg = 0; cg < 4; ++cg) ac[cg] = (f32x4){0.f, 0.f, 0.f, 0.f};
    #pragma unroll
    for (int h2 = 0; h2 < 2; ++h2) {
        const int d0 = lq * 8 + h2 * 32;
        #pragma unroll
        for (int cg = 0; cg < 4; ++cg) {
            const int key = cg * 16 + l15;
            const bf16x8 bB = *(const bf16x8*)&kt[key * 64 + (d0 ^ ((key & 7) << 3))];
            ac[cg] = MFMA16(quA[h2], bB, ac[cg]);
        }
    }
    // --- MFMA: BD = QV @ band^T ---
    f32x4 bd[8];
    #pragma unroll
    for (int cg = 0; cg < 8; ++cg) bd[cg] = (f32x4){0.f, 0.f, 0.f, 0.f};
    #pragma unroll
    for (int h2 = 0; h2 < 2; ++h2) {
        const int d0 = lq * 8 + h2 * 32;
        #pragma unroll
        for (int cg = 0; cg < 8; ++cg) {
            const int dd = cg * 16 + l15;
            const bf16x8 bB = *(const bf16x8*)&band[dd * 64 + (d0 ^ ((dd & 7) << 3))];
            bd[cg] = MFMA16(qvA[h2], bB, bd[cg]);
        }
    }
    // --- BD row 64 into registers (wrap source from qlb=64) ---
    float rv = 0.f;
    const int rdd = tid >> 1;
    if (MODE != 0 && tid < 128) {
        const int half = tid & 1;
        #pragma unroll
        for (int c2 = 0; c2 < 4; ++c2) {
            const int d0 = half * 32 + c2 * 8;
            const bf16x8 bv = *(const bf16x8*)&band[rdd * 64 + (d0 ^ ((rdd & 7) << 3))];
            #pragma unroll
            for (int e = 0; e < 8; ++e)
                rv = fmaf(bf2f((u16)bv[e]), qv64f[d0 + e], rv);
        }
        rv += __shfl_xor(rv, 1, 64);
    }
    __syncthreads();   // all kt/band reads complete

    // --- scatter BD -> sc (score layout), r64 ---
    #pragma unroll
    for (int cg = 0; cg < 8; ++cg) {
        const int dd = cg * 16 + l15;
        const int diff_e = diff_base + dd;
        #pragma unroll
        for (int r = 0; r < 4; ++r) {
            const int qlb = w * 16 + lq * 4 + r;
            const int key_n = dd + qlb - 63;
            const float val = bd[cg][r];
            if (MODE == 0) {
                if ((unsigned)key_n < 64u) sc[qlb * 66 + key_n] = val;
            } else if (MODE == 1) {
                const int key_w = key_n - 1;
                if ((unsigned)key_w < 64u && qlb >= 1) sc[(qlb - 1) * 66 + key_w] = val;
            } else {
                if (diff_e <= 512) {
                    if ((unsigned)key_n < 64u) sc[qlb * 66 + key_n] = val;
                } else if (diff_e >= 514) {
                    const int key_w = key_n - 1;
                    if ((unsigned)key_w < 64u && qlb >= 1) sc[(qlb - 1) * 66 + key_w] = val;
                }
            }
        }
    }
    if (MODE != 0 && tid < 128 && (tid & 1) == 0) r64s[rdd] = rv;
    __syncthreads();   // scatter visible

    // --- softmax (online) ---
    float f_r[4];
    #pragma unroll
    for (int r = 0; r < 4; ++r) {
        const int q16 = lq * 4 + r;
        const int ql  = w * 16 + q16;
        u64 mw = ~0ull;
        if (j0 >= M_) mw = mrow64[(size_t)ql * 32 + ((j0 - M_) >> 6)];
        float sr[4];
        #pragma unroll
        for (int cg = 0; cg < 4; ++cg) {
            const int key = cg * 16 + l15;
            float bdv;
            if (MODE == 0) bdv = sc[ql * 66 + key];
            else if (MODE == 1) bdv = (ql == 63) ? r64s[key] : sc[ql * 66 + key];
            else {
                const int diff = (j0 - i0) + key - ql;
                if (diff == 513) bdv = 0.f;
                else if (diff >= 514 && ql == 63) bdv = r64s[key];
                else bdv = sc[ql * 66 + key];
            }
            float s = (ac[cg][r] + bdv) * 0.125f;
            if (j0 >= M_) {
                if (!((mw >> key) & 1ull)) s -= 1.0e9f;
            }
            sr[cg] = s;
        }
        float mx = fmaxf(fmaxf(sr[0], sr[1]), fmaxf(sr[2], sr[3]));
        mx = fmaxf(mx, __shfl_xor(mx, 1, 64));
        mx = fmaxf(mx, __shfl_xor(mx, 2, 64));
        mx = fmaxf(mx, __shfl_xor(mx, 4, 64));
        mx = fmaxf(mx, __shfl_xor(mx, 8, 64));
        const float mn = fmaxf(m_run[r], mx);
        const float fr = __expf(m_run[r] - mn);
        m_run[r] = mn;
        float lt = 0.f;
        #pragma unroll
        for (int cg = 0; cg < 4; ++cg) {
            const float p = __expf(sr[cg] - mn);
            lt += p;
            plds[w * 1024 + q16 * 64 + ((cg * 16 + l15) ^ ((q16 & 7) << 3))] = f2bf(p);
        }
        lt += __shfl_xor(lt, 1, 64);
        lt += __shfl_xor(lt, 2, 64);
        lt += __shfl_xor(lt, 4, 64);
        lt += __shfl_xor(lt, 8, 64);
        l_run[r] = l_run[r] * fr + lt;
        f_r[r] = fr;
    }
    #pragma unroll
    for (int cg = 0; cg < 4; ++cg)
        #pragma unroll
        for (int r = 0; r < 4; ++r) oacc[cg][r] *= f_r[r];
    __syncthreads();   // plds / vt ready

    // --- MFMA: O += P @ V ---
    #pragma unroll
    for (int kh = 0; kh < 2; ++kh) {
        const int key0 = lq * 8 + kh * 32;
        const bf16x8 pA = *(const bf16x8*)&plds[w * 1024 + l15 * 64 + (key0 ^ ((l15 & 7) << 3))];
        #pragma unroll
        for (int cg = 0; cg < 4; ++cg) {
            const int d = cg * 16 + l15;
            const bf16x8 vB = *(const bf16x8*)&vt[d * 64 + (key0 ^ ((d & 7) << 3))];
            oacc[cg] = MFMA16(pA, vB, oacc[cg]);
        }
    }
}

__global__ __launch_bounds__(256, 3)
void attn_mfma(const u16* __restrict__ qu, const u16* __restrict__ qv,
               const u16* __restrict__ kb, const u16* __restrict__ vb,
               const u16* __restrict__ kr, const u64* __restrict__ mbq,
               float* __restrict__ ob)
{
    __shared__ __align__(16) u16  ktband[64 * 64 + 128 * 64]; // kt | band; sc aliases
    __shared__ __align__(16) u16  vt[64 * 64];
    __shared__ __align__(16) u16  plds[4 * 16 * 64];
    __shared__ __align__(16) float r64s[64];
    __shared__ __align__(16) float qv64f[64];

    u16* kt = ktband;
    u16* band = ktband + 4096;
    float* sc = (float*)ktband;       // 64*66 floats = 16896 B <= 24576 B

    const int tid = threadIdx.x;
    const int w = tid >> 6, lane = tid & 63;
    const int l15 = lane & 15, lq = lane >> 4;
    const int h = blockIdx.y, b = blockIdx.z;
    const int i0 = blockIdx.x * 64;

    const size_t bh = (size_t)(b * H_ + h);
    const u16* qub = qu + bh * S_ * 64;
    const u16* qvb = qv + bh * S_ * 64;
    const u16* kbb = kb + bh * K_ * 64;
    const u16* vbb = vb + bh * K_ * 64;
    const u16* krb = kr + (size_t)h * K_ * 64;
    const u64* mrow64 = mbq + ((size_t)b * S_ + i0) * 32;

    bf16x8 quA[2], qvA[2];
    {
        const size_t qr = (size_t)(i0 + w * 16 + l15) * 64 + lq * 8;
        quA[0] = *(const bf16x8*)(qub + qr);
        quA[1] = *(const bf16x8*)(qub + qr + 32);
        qvA[0] = *(const bf16x8*)(qvb + qr);
        qvA[1] = *(const bf16x8*)(qvb + qr + 32);
    }
    if (tid < 64) {
        int qr = i0 + 64; if (qr > S_ - 1) qr = S_ - 1;   // clamped row never consumed
        qv64f[tid] = bf2f(qvb[(size_t)qr * 64 + tid]);
    }

    float m_run[4], l_run[4];
    #pragma unroll
    for (int r = 0; r < 4; ++r) { m_run[r] = -3.0e38f; l_run[r] = 0.f; }
    f32x4 oacc[4];
    #pragma unroll
    for (int cg = 0; cg < 4; ++cg) oacc[cg] = (f32x4){0.f, 0.f, 0.f, 0.f};

    const int ti = i0 >> 6;
    const int t1 = (ti + 8  < 40) ? ti + 8  : 40;   // mode0: [0,t1)
    const int t2 = (ti + 10 < 40) ? ti + 10 : 40;   // mode2: [t1,t2), mode1: [t2,40)

    for (int t = 0; t < t1; ++t)
        attn_tile_step<0>(t, i0, tid, kbb, vbb, krb, mrow64, quA, qvA,
                          kt, band, vt, sc, r64s, plds, qv64f, oacc, m_run, l_run);
    for (int t = t1; t < t2; ++t)
        attn_tile_step<2>(t, i0, tid, kbb, vbb, krb, mrow64, quA, qvA,
                          kt, band, vt, sc, r64s, plds, qv64f, oacc, m_run, l_run);
    for (int t = t2; t < 40; ++t)
        attn_tile_step<1>(t, i0, tid, kbb, vbb, krb, mrow64, quA, qvA,
                          kt, band, vt, sc, r64s, plds, qv64f, oacc, m_run, l_run);

    #pragma unroll
    for (int cg = 0; cg < 4; ++cg)
        #pragma unroll
        for (int r = 0; r < 4; ++r) {
            const int ql = w * 16 + lq * 4 + r;
            ob[((size_t)b * S_ + i0 + ql) * DM_ + h * 64 + cg * 16 + l15] =
                oacc[cg][r] / l_run[r];
        }
}

// ---------------------------------------------------------------------------
extern "C" void kernel_launch(void* const* d_in, const int* in_sizes, int n_in,
                              void* d_out, int out_size, void* d_ws, size_t ws_size,
                              hipStream_t stream)
{
    const float* x     = (const float*)d_in[0];
    const float* mem   = (const float*)d_in[1];
    const float* rpe   = (const float*)d_in[2];
    const int*   amask = (const int*)  d_in[3];
    const float* Wq_w  = (const float*)d_in[5];
    const float* Wq_b  = (const float*)d_in[6];
    const float* Wke_w = (const float*)d_in[7];
    const float* Wke_b = (const float*)d_in[8];
    const float* Wv_w  = (const float*)d_in[9];
    const float* Wv_b  = (const float*)d_in[10];
    const float* Wkr_w = (const float*)d_in[11];
    const float* Wkr_b = (const float*)d_in[12];
    const float* u     = (const float*)d_in[13];
    const float* v     = (const float*)d_in[14];
    const float* Wo_w  = (const float*)d_in[15];
    const float* Wo_b  = (const float*)d_in[16];
    float* out = (float*)d_out;

    // workspace layout (u16 units unless noted)
    u16* quB  = (u16*)d_ws;                 // 3,145,728
    u16* qvB  = quB + 3145728;              // 3,145,728
    u16* kbB  = qvB + 3145728;              // 3,932,160
    u16* vbB  = kbB + 3932160;              // 3,932,160
    u16* krB  = vbB + 3932160;              // 1,966,080
    u64* mbB  = (u64*)(krB + 1966080);      // 131,072 u64
    u16* castB = (u16*)(mbB + 131072);
    u16* kvinB = castB;                     // 3,932,160 (mem rows then x rows)
    u16* rpeB  = kvinB + 3932160;           // 1,966,080
    u16* WqB   = rpeB + 1966080;            // 589,824
    u16* WkeB  = WqB + 589824;
    u16* WvB   = WkeB + 589824;
    u16* WkrB  = WvB + 589824;
    float* obB = (float*)castB;             // aliases cast region (dead after gemms)

    maskpack<<<B_ * S_ * S_ / 256, 256, 0, stream>>>(amask, mbB);

    Cast7 c;
    c.src[0] = mem;   c.dst[0] = kvinB;          c.n4[0] = 786432 / 4;
    c.src[1] = x;     c.dst[1] = kvinB + 786432; c.n4[1] = 3145728 / 4;
    c.src[2] = rpe;   c.dst[2] = rpeB;           c.n4[2] = 1966080 / 4;
    c.src[3] = Wq_w;  c.dst[3] = WqB;            c.n4[3] = 589824 / 4;
    c.src[4] = Wke_w; c.dst[4] = WkeB;           c.n4[4] = 589824 / 4;
    c.src[5] = Wv_w;  c.dst[5] = WvB;            c.n4[5] = 589824 / 4;
    c.src[6] = Wkr_w; c.dst[6] = WkrB;           c.n4[6] = 589824 / 4;
    castk<<<dim3(3072, 7), 256, 0, stream>>>(c);

    gemm_bf16<0><<<dim3(6, 32), 256, 0, stream>>>(
        WqB, kvinB + 786432, Wq_b, u, v, quB, qvB);
    gemm_bf16<1><<<dim3(6, 40), 256, 0, stream>>>(
        WkeB, kvinB, Wke_b, nullptr, nullptr, kbB, nullptr);
    gemm_bf16<1><<<dim3(6, 40), 256, 0, stream>>>(
        WvB, kvinB, Wv_b, nullptr, nullptr, vbB, nullptr);
    gemm_bf16<2><<<dim3(6, 20), 256, 0, stream>>>(
        WkrB, rpeB, Wkr_b, nullptr, nullptr, krB, nullptr);

    attn_mfma<<<dim3(S_ / 64, H_, B_), 256, 0, stream>>>(
        quB, qvB, kbB, vbB, krB, mbB, obB);

    gemm_o<<<dim3(S_ * B_ / 128, DM_ / 64), 256, 0, stream>>>(
        obB, Wo_w, Wo_b, out);
}